// Round 1
// baseline (373.722 us; speedup 1.0000x reference)
//
#include <hip/hip_runtime.h>
#include <math.h>

// Problem geometry (fixed by reference):
//   A: (B=8, M=16, T=64, H=64, W=64) fp32
//   U: (8, 16, C=2, 64, 64, 64) fp32
//   out: (8, 80, 64, 64) fp32 = concat[A_last, A_fast, A_slow, A_deriv, E_temp] on axis 1
#define T_DIM 64
#define HW    4096            // 64*64 plane
#define SPLITS 4              // quarter-plane per block

__device__ __forceinline__ void ema_step(float4& acc, const float4& x, float a, float oma) {
    acc.x = a * acc.x + oma * x.x;
    acc.y = a * acc.y + oma * x.y;
    acc.z = a * acc.z + oma * x.z;
    acc.w = a * acc.w + oma * x.w;
}

__global__ __launch_bounds__(256) void temporal_summarizer_kernel(
        const float* __restrict__ A, const float* __restrict__ U,
        float* __restrict__ out) {
    constexpr float AF = 0.74f, AS = 0.95f;
    constexpr float OMF = 1.0f - 0.74f, OMS = 1.0f - 0.95f;
    constexpr float EPS = 1e-6f;

    const int blk   = blockIdx.x;
    const int split = blk % SPLITS;          // which quarter of the HW plane
    const int bm    = blk / SPLITS;          // 0..127  (b*16 + m)
    const int m     = bm & 15;
    const int b     = bm >> 4;

    const int pix = split * (HW / SPLITS) + threadIdx.x * 4;   // float offset within plane

    const float* pA = A + (size_t)bm * (T_DIM * HW) + pix;

    float4 fast = make_float4(0.f, 0.f, 0.f, 0.f);
    float4 slow = make_float4(0.f, 0.f, 0.f, 0.f);
    float4 a62  = make_float4(0.f, 0.f, 0.f, 0.f);
    float4 a63  = make_float4(0.f, 0.f, 0.f, 0.f);

    #pragma unroll 8
    for (int t = 0; t < T_DIM; ++t) {
        float4 x = *(const float4*)(pA + (size_t)t * HW);
        ema_step(fast, x, AF, OMF);
        ema_step(slow, x, AS, OMS);
        if (t == T_DIM - 2) a62 = x;
        if (t == T_DIM - 1) a63 = x;
    }

    // U slices: c=0/1 at t=61 and t=63
    const float* pU = U + (size_t)bm * (2 * T_DIM * HW) + pix;
    float4 u0l = *(const float4*)(pU + 63 * HW);                 // c=0, t=-1
    float4 u0m = *(const float4*)(pU + 61 * HW);                 // c=0, t=-3
    float4 u1l = *(const float4*)(pU + (size_t)T_DIM * HW + 63 * HW);
    float4 u1m = *(const float4*)(pU + (size_t)T_DIM * HW + 61 * HW);

    float4 et;
    {
        float* e = &et.x;
        const float* p0l = &u0l.x; const float* p0m = &u0m.x;
        const float* p1l = &u1l.x; const float* p1m = &u1m.x;
        #pragma unroll
        for (int i = 0; i < 4; ++i) {
            float pq0 = 0.5f * (p0l[i] - p0m[i]);
            float er  = sqrtf(fmaxf(p0l[i] * p0l[i] + pq0 * pq0, EPS));
            float pq1 = 0.5f * (p1l[i] - p1m[i]);
            float ei  = sqrtf(fmaxf(p1l[i] * p1l[i] + pq1 * pq1, EPS));
            e[i] = sqrtf(fmaxf(er * er + ei * ei, EPS));
        }
    }

    float4 deriv = make_float4(a63.x - a62.x, a63.y - a62.y,
                               a63.z - a62.z, a63.w - a62.w);

    // out[b, g*16 + m, h, w]
    float* ob = out + ((size_t)b * 80) * HW + (size_t)m * HW + pix;
    *(float4*)(ob + 0 * 16 * HW) = a63;    // A_last
    *(float4*)(ob + 1 * 16 * HW) = fast;   // A_fast
    *(float4*)(ob + 2 * 16 * HW) = slow;   // A_slow
    *(float4*)(ob + 3 * 16 * HW) = deriv;  // A_deriv
    *(float4*)(ob + 4 * 16 * HW) = et;     // E_temp
}

extern "C" void kernel_launch(void* const* d_in, const int* in_sizes, int n_in,
                              void* d_out, int out_size, void* d_ws, size_t ws_size,
                              hipStream_t stream) {
    const float* A = (const float*)d_in[0];
    const float* U = (const float*)d_in[1];
    float* out = (float*)d_out;
    dim3 grid(8 * 16 * SPLITS);   // 512 blocks
    dim3 block(256);
    temporal_summarizer_kernel<<<grid, block, 0, stream>>>(A, U, out);
}